// Round 3
// baseline (18727.568 us; speedup 1.0000x reference)
//
#include <hip/hip_runtime.h>
#include <math.h>

#define BB 64
#define SS 512
#define EE 512
#define HH 1024
#define NWG 256

// ws layout:
//   INP   [S][H][B] float  (128 MiB)      inp[t][j][b]
//   Wpack [H][256][12] float (12 MiB)     per k, per jg: {Wf[4jg..+3][k], Wh[4jg..+3][k], Wo[4jg..+3][k]}
//   h0,h1,hsel : [H][B] float (256 KiB)   h[k][b]
//   lin   float4[H/4][B]  (round-1 final layout: flat (j4*64+b)*4+c)
//   flags [NWG] + go : unsigned

#define DOT4(acc, u, v) acc += (u).x*(v).x + (u).y*(v).y + (u).z*(v).z + (u).w*(v).w

// ---------------- weight pre-pack (one-time, 3072 rows) ----------------
__global__ __launch_bounds__(256) void pack_kernel(
    const float* __restrict__ Wf, const float* __restrict__ Wh,
    const float* __restrict__ Wo, float* __restrict__ Wpack)
{
    int r = blockIdx.x;            // 0..3071
    int m = r >> 10;               // 0=Wf 1=Wh 2=Wo
    int j = r & 1023;
    const float* src = (m == 0 ? Wf : (m == 1 ? Wh : Wo)) + (size_t)j * HH;
    float4 v = reinterpret_cast<const float4*>(src)[threadIdx.x];   // k = 4*tid..+3
    int jg = j >> 2;
    int c  = (j & 3) + m * 4;
    size_t base = (size_t)(4 * threadIdx.x) * 3072 + jg * 12 + c;
    Wpack[base         ] = v.x;
    Wpack[base + 3072  ] = v.y;
    Wpack[base + 2*3072] = v.z;
    Wpack[base + 3*3072] = v.w;
}

// ---------------- input-gate GEMM (parallel, hoisted) ----------------
__global__ __launch_bounds__(512) void gemm1_kernel(
    const int* __restrict__ x, const float* __restrict__ emb,
    const float* __restrict__ Wi, const float* __restrict__ bi,
    float* __restrict__ INP)
{
    int t    = blockIdx.y;
    int lane = threadIdx.x & 63;                                   // batch b
    int wave = __builtin_amdgcn_readfirstlane(threadIdx.x >> 6);   // 0..7
    int j4   = blockIdx.x * 8 + wave;                              // 0..255

    int row = x[lane * SS + t];
    const float4* e  = reinterpret_cast<const float4*>(emb + (size_t)row * EE);
    const float4* w0 = reinterpret_cast<const float4*>(Wi + (size_t)(j4*4+0) * EE);
    const float4* w1 = reinterpret_cast<const float4*>(Wi + (size_t)(j4*4+1) * EE);
    const float4* w2 = reinterpret_cast<const float4*>(Wi + (size_t)(j4*4+2) * EE);
    const float4* w3 = reinterpret_cast<const float4*>(Wi + (size_t)(j4*4+3) * EE);

    float a0 = 0.f, a1 = 0.f, a2 = 0.f, a3 = 0.f;
    #pragma unroll 8
    for (int k4 = 0; k4 < EE/4; ++k4) {
        float4 ev = e[k4];
        float4 w;
        w = w0[k4]; DOT4(a0, ev, w);
        w = w1[k4]; DOT4(a1, ev, w);
        w = w2[k4]; DOT4(a2, ev, w);
        w = w3[k4]; DOT4(a3, ev, w);
    }
    float4 bv = *reinterpret_cast<const float4*>(bi + j4*4);
    size_t base = ((size_t)t * HH + j4*4) * 64 + lane;
    INP[base + 0*64] = fmaxf(a0 + bv.x, 0.f);
    INP[base + 1*64] = fmaxf(a1 + bv.y, 0.f);
    INP[base + 2*64] = fmaxf(a2 + bv.z, 0.f);
    INP[base + 3*64] = fmaxf(a3 + bv.w, 0.f);
}

// ---------------- fence-free grid barrier ----------------
__device__ __forceinline__ void grid_bar(unsigned* flags, unsigned* go, int wg, unsigned e) {
    asm volatile("s_waitcnt vmcnt(0)" ::: "memory");   // drain our sc1 h-stores
    __syncthreads();
    const int tid = threadIdx.x;
    unsigned guard = 0;
    if (wg == 0) {
        if (tid >= 1 && tid < NWG) {
            while (__hip_atomic_load(&flags[tid], __ATOMIC_RELAXED, __HIP_MEMORY_SCOPE_AGENT) < e
                   && ++guard < (1u << 20)) {}
        }
        __syncthreads();
        if (tid == 0) __hip_atomic_store(go, e, __ATOMIC_RELAXED, __HIP_MEMORY_SCOPE_AGENT);
    } else {
        if (tid == 0) {
            __hip_atomic_store(&flags[wg], e, __ATOMIC_RELAXED, __HIP_MEMORY_SCOPE_AGENT);
            while (__hip_atomic_load(go, __ATOMIC_RELAXED, __HIP_MEMORY_SCOPE_AGENT) < e
                   && ++guard < (1u << 20)) {}
        }
        __syncthreads();
    }
}

// sc1 (agent-coherent) h load: hits shared L3, bypasses stale per-XCD L2
#define LDH(i, base, off) \
    asm volatile("global_load_dword %0, %1, off offset:" off " sc1" \
                 : "=v"(hv[i]) : "v"(base))
#define LDB16(base, s) \
    LDH(s+0,  base, "0");    LDH(s+1,  base, "256");  LDH(s+2,  base, "512");  LDH(s+3,  base, "768"); \
    LDH(s+4,  base, "1024"); LDH(s+5,  base, "1280"); LDH(s+6,  base, "1536"); LDH(s+7,  base, "1792"); \
    LDH(s+8,  base, "2048"); LDH(s+9,  base, "2304"); LDH(s+10, base, "2560"); LDH(s+11, base, "2816"); \
    LDH(s+12, base, "3072"); LDH(s+13, base, "3328"); LDH(s+14, base, "3584"); LDH(s+15, base, "3840");

// ---------------- persistent recurrence ----------------
__global__ __launch_bounds__(1024, 4) void seq_kernel(
    const float* __restrict__ INP, const float* __restrict__ Wpack,
    const float* __restrict__ bfv, const float* __restrict__ bhv,
    const int* __restrict__ lengths,
    float* __restrict__ h0, float* __restrict__ h1,
    float* __restrict__ hsel,
    unsigned* __restrict__ flags, unsigned* __restrict__ go)
{
    __shared__ float pf[16][4][64];
    __shared__ float ph[16][4][64];

    const int tid  = threadIdx.x;
    const int lane = tid & 63;                                   // batch b
    const int kq   = __builtin_amdgcn_readfirstlane(tid >> 6);   // 0..15 K-slice
    const int jg   = blockIdx.x;                                 // col quad

    const int fc = tid >> 6, fb = tid & 63;
    float bf_c = 0.f, bh_c = 0.f;
    int   mylen = 0;
    if (tid < 256) { bf_c = bfv[jg*4+fc]; bh_c = bhv[jg*4+fc]; mylen = lengths[fb]; }

    const float* wpk = Wpack + (size_t)(kq * 64) * 3072 + jg * 12;

    for (int t = 0; t < SS; ++t) {
        const float* hin  = (t & 1) ? h1 : h0;
        float*       hout = (t & 1) ? h0 : h1;
        const float* b0 = hin + (size_t)(kq*64 +  0) * 64 + lane;
        const float* b1 = hin + (size_t)(kq*64 + 16) * 64 + lane;
        const float* b2 = hin + (size_t)(kq*64 + 32) * 64 + lane;
        const float* b3 = hin + (size_t)(kq*64 + 48) * 64 + lane;

        float hv[64];
        LDB16(b0, 0)  LDB16(b1, 16)  LDB16(b2, 32)  LDB16(b3, 48)
        asm volatile("s_waitcnt vmcnt(0)" ::: "memory");
        __builtin_amdgcn_sched_barrier(0);

        float f0=0.f,f1=0.f,f2=0.f,f3=0.f, g0=0.f,g1=0.f,g2=0.f,g3=0.f;
        #pragma unroll
        for (int kk = 0; kk < 64; ++kk) {
            const float* w = wpk + (size_t)kk * 3072;
            f0 = fmaf(hv[kk], w[0], f0);
            f1 = fmaf(hv[kk], w[1], f1);
            f2 = fmaf(hv[kk], w[2], f2);
            f3 = fmaf(hv[kk], w[3], f3);
            g0 = fmaf(hv[kk], w[4], g0);
            g1 = fmaf(hv[kk], w[5], g1);
            g2 = fmaf(hv[kk], w[6], g2);
            g3 = fmaf(hv[kk], w[7], g3);
        }
        pf[kq][0][lane]=f0; pf[kq][1][lane]=f1; pf[kq][2][lane]=f2; pf[kq][3][lane]=f3;
        ph[kq][0][lane]=g0; ph[kq][1][lane]=g1; ph[kq][2][lane]=g2; ph[kq][3][lane]=g3;
        __syncthreads();

        if (tid < 256) {
            float iv = INP[((size_t)t*HH + jg*4 + fc)*64 + fb];
            float sf = bf_c, sh = bh_c;
            #pragma unroll
            for (int q = 0; q < 16; ++q) { sf += pf[q][fc][fb]; sh += ph[q][fc][fb]; }
            float hn = 1.f/(1.f+expf(-sf)) + tanhf(sh)*iv;
            float* haddr = hout + (size_t)(jg*4 + fc)*64 + fb;
            asm volatile("global_store_dword %0, %1, off sc1" :: "v"(haddr), "v"(hn) : "memory");
            if (t == mylen - 1) hsel[(size_t)(jg*4 + fc)*64 + fb] = hn;   // plain: read post-kernel
        }
        grid_bar(flags, go, jg, (unsigned)(t + 1));
    }
}

// ---------------- output projection (post-kernel, plain cached) ----------------
__global__ __launch_bounds__(1024) void outproj_kernel(
    const float* __restrict__ hsel, const float* __restrict__ Wpack,
    const float* __restrict__ bov, float* __restrict__ lin)
{
    __shared__ float pf[16][4][64];
    const int tid  = threadIdx.x;
    const int lane = tid & 63;
    const int kq   = __builtin_amdgcn_readfirstlane(tid >> 6);
    const int jg   = blockIdx.x;

    const float* wpk = Wpack + (size_t)(kq * 64) * 3072 + jg * 12 + 8;
    const float* hb  = hsel + (size_t)(kq * 64) * 64 + lane;

    float a0=0.f,a1=0.f,a2=0.f,a3=0.f;
    #pragma unroll
    for (int kk = 0; kk < 64; ++kk) {
        float hvv = hb[(size_t)kk * 64];
        const float* w = wpk + (size_t)kk * 3072;
        a0 = fmaf(hvv, w[0], a0);
        a1 = fmaf(hvv, w[1], a1);
        a2 = fmaf(hvv, w[2], a2);
        a3 = fmaf(hvv, w[3], a3);
    }
    pf[kq][0][lane]=a0; pf[kq][1][lane]=a1; pf[kq][2][lane]=a2; pf[kq][3][lane]=a3;
    __syncthreads();

    const int fc = tid >> 6, fb = tid & 63;
    if (tid < 256) {
        float s = bov[jg*4+fc];
        #pragma unroll
        for (int q = 0; q < 16; ++q) s += pf[q][fc][fb];
        lin[((size_t)jg*64 + fb)*4 + fc] = s;    // round-1 final layout
    }
}

__global__ __launch_bounds__(64) void final_kernel(
    const float4* __restrict__ lin, const float* __restrict__ Wlin,
    const float* __restrict__ blin, float* __restrict__ out)
{
    int b = threadIdx.x;
    float l0 = blin[0], l1 = blin[1];
    const float4* w0 = reinterpret_cast<const float4*>(Wlin);
    const float4* w1 = reinterpret_cast<const float4*>(Wlin) + 256;
    #pragma unroll 4
    for (int j4 = 0; j4 < 256; ++j4) {
        float4 v = lin[j4*64 + b];
        float4 wa = w0[j4], wb = w1[j4];
        DOT4(l0, v, wa);
        DOT4(l1, v, wb);
    }
    float m   = fmaxf(l0, l1);
    float lse = m + logf(expf(l0 - m) + expf(l1 - m));
    out[b*2 + 0] = l0 - lse;
    out[b*2 + 1] = l1 - lse;
}

extern "C" void kernel_launch(void* const* d_in, const int* in_sizes, int n_in,
                              void* d_out, int out_size, void* d_ws, size_t ws_size,
                              hipStream_t stream) {
    (void)in_sizes; (void)n_in; (void)out_size; (void)ws_size;
    const int*   x       = (const int*)  d_in[0];
    const int*   lengths = (const int*)  d_in[1];
    const float* emb     = (const float*)d_in[2];
    const float* Wi      = (const float*)d_in[3];
    const float* bi      = (const float*)d_in[4];
    const float* Wf      = (const float*)d_in[5];
    const float* bf      = (const float*)d_in[6];
    const float* Wh      = (const float*)d_in[7];
    const float* bh      = (const float*)d_in[8];
    const float* Wo      = (const float*)d_in[9];
    const float* bo      = (const float*)d_in[10];
    const float* Wlin    = (const float*)d_in[11];
    const float* blin    = (const float*)d_in[12];
    float* out = (float*)d_out;

    char* ws = (char*)d_ws;
    const size_t INP_BYTES  = (size_t)SS * HH * 64 * sizeof(float);   // 128 MiB
    const size_t PACK_BYTES = (size_t)HH * 256 * 12 * sizeof(float);  // 12 MiB
    float*    INP   = (float*)ws;
    float*    Wpack = (float*)(ws + INP_BYTES);
    float*    h0    = (float*)(ws + INP_BYTES + PACK_BYTES);
    float*    h1    = h0 + HH*64;
    float*    hsel  = h1 + HH*64;
    float*    lin   = hsel + HH*64;
    unsigned* flags = (unsigned*)(lin + HH*64);
    unsigned* go    = flags + NWG;

    hipMemsetAsync(h0, 0, HH*64*sizeof(float), stream);
    hipMemsetAsync(flags, 0, (NWG + 16)*sizeof(unsigned), stream);

    pack_kernel<<<3072, 256, 0, stream>>>(Wf, Wh, Wo, Wpack);
    gemm1_kernel<<<dim3(32, 512), 512, 0, stream>>>(x, emb, Wi, bi, INP);

    void* args[] = {&INP, &Wpack, &bf, &bh, &lengths, &h0, &h1, &hsel, &flags, &go};
    hipLaunchCooperativeKernel((const void*)seq_kernel, dim3(NWG), dim3(1024),
                               args, 0, stream);

    outproj_kernel<<<NWG, 1024, 0, stream>>>(hsel, Wpack, bo, lin);
    final_kernel<<<1, 64, 0, stream>>>((const float4*)lin, Wlin, blin, out);
}

// Round 4
// 8790.945 us; speedup vs baseline: 2.1303x; 2.1303x over previous
//
#include <hip/hip_runtime.h>
#include <math.h>

#define BB 64
#define SS 512
#define EE 512
#define HH 1024

typedef __attribute__((ext_vector_type(8))) short bf16x8;
typedef __attribute__((ext_vector_type(4))) float f32x4;

#define DOT4(acc, u, v) acc += (u).x*(v).x + (u).y*(v).y + (u).z*(v).z + (u).w*(v).w

__device__ __forceinline__ unsigned short bf16_hi(float x) {
    union { float f; unsigned u; } c; c.f = x;
    unsigned r = c.u + 0x7fffu + ((c.u >> 16) & 1u);   // RNE
    return (unsigned short)(r >> 16);
}
__device__ __forceinline__ float bf16_f(unsigned short h) {
    union { unsigned u; float f; } c; c.u = ((unsigned)h) << 16;
    return c.f;
}

// ---- pack Wf|Wh (cols interleaved: jcat=2j -> Wf col j, 2j+1 -> Wh col j)
// into MFMA B-fragment order, split bf16 hi/lo.
// Wp[((n*32+ks)*64+l)*8+i] = Wcat[k = ks*32+(l>>4)*8+i][jcat = 16n+(l&15)]
__global__ __launch_bounds__(64) void packw_kernel(
    const float* __restrict__ Wf, const float* __restrict__ Wh,
    unsigned short* __restrict__ Wph, unsigned short* __restrict__ Wpl)
{
    int n = blockIdx.x, ks = blockIdx.y, l = threadIdx.x;
    int jcat  = 16*n + (l & 15);
    int kbase = ks*32 + ((l >> 4) << 3);
    const float* src = ((jcat & 1) ? Wh : Wf) + (size_t)(jcat >> 1)*HH + kbase;
    size_t o = ((size_t)(n*32 + ks)*64 + l) * 8;
    #pragma unroll
    for (int i = 0; i < 8; ++i) {
        float x = src[i];
        unsigned short hi = bf16_hi(x);
        Wph[o+i] = hi;
        Wpl[o+i] = bf16_hi(x - bf16_f(hi));
    }
}

// ---- input gate (hoisted, fp32 VALU): INP[t][b][j] = relu(emb[x[b][t]] . Wi[j] + bi[j])
__global__ __launch_bounds__(512) void gemm1_kernel(
    const int* __restrict__ x, const float* __restrict__ emb,
    const float* __restrict__ Wi, const float* __restrict__ bi,
    float* __restrict__ INP)
{
    int t    = blockIdx.y;
    int lane = threadIdx.x & 63;                                   // b
    int wave = __builtin_amdgcn_readfirstlane(threadIdx.x >> 6);   // 0..7
    int j4   = blockIdx.x * 8 + wave;                              // 0..255

    int row = x[lane * SS + t];
    const float4* e  = reinterpret_cast<const float4*>(emb + (size_t)row * EE);
    const float4* w0 = reinterpret_cast<const float4*>(Wi + (size_t)(j4*4+0) * EE);
    const float4* w1 = reinterpret_cast<const float4*>(Wi + (size_t)(j4*4+1) * EE);
    const float4* w2 = reinterpret_cast<const float4*>(Wi + (size_t)(j4*4+2) * EE);
    const float4* w3 = reinterpret_cast<const float4*>(Wi + (size_t)(j4*4+3) * EE);

    float a0 = 0.f, a1 = 0.f, a2 = 0.f, a3 = 0.f;
    #pragma unroll 8
    for (int k4 = 0; k4 < EE/4; ++k4) {
        float4 ev = e[k4];
        float4 w;
        w = w0[k4]; DOT4(a0, ev, w);
        w = w1[k4]; DOT4(a1, ev, w);
        w = w2[k4]; DOT4(a2, ev, w);
        w = w3[k4]; DOT4(a3, ev, w);
    }
    float4 bv = *reinterpret_cast<const float4*>(bi + j4*4);
    float4 r;
    r.x = fmaxf(a0 + bv.x, 0.f);
    r.y = fmaxf(a1 + bv.y, 0.f);
    r.z = fmaxf(a2 + bv.z, 0.f);
    r.w = fmaxf(a3 + bv.w, 0.f);
    *reinterpret_cast<float4*>(INP + ((size_t)t*BB + lane)*HH + j4*4) = r;
}

// ---- one recurrence step: C[64x2048] = h[64x1024] @ Wcat, split-bf16 MFMA.
// 128 WGs x 1024 thr (16 waves = 4 M-tiles x 4-way K-split).
__global__ __launch_bounds__(1024) void step_kernel(
    const unsigned short* __restrict__ hhi_in, const unsigned short* __restrict__ hlo_in,
    unsigned short* __restrict__ hhi_out, unsigned short* __restrict__ hlo_out,
    const unsigned short* __restrict__ Wph, const unsigned short* __restrict__ Wpl,
    const float* __restrict__ INPt,
    const float* __restrict__ bfv, const float* __restrict__ bhv,
    const int* __restrict__ lengths, float* __restrict__ hselT, int t)
{
    __shared__ f32x4 red[3][4][64];

    const int n   = blockIdx.x;                                  // 16-col group of Wcat
    const int tid = threadIdx.x;
    const int l   = tid & 63;
    const int w   = __builtin_amdgcn_readfirstlane(tid >> 6);    // 0..15
    const int m   = w & 3;                                       // M-tile (rows 16m..+15)
    const int kk  = w >> 2;                                      // K-split 0..3

    const int row = 16*m + (l & 15);
    const size_t abase = (size_t)row*HH + ((l >> 4) << 3);
    const bf16x8* Ah = reinterpret_cast<const bf16x8*>(hhi_in + abase);
    const bf16x8* Al = reinterpret_cast<const bf16x8*>(hlo_in + abase);
    const bf16x8* Bh = reinterpret_cast<const bf16x8*>(Wph) + (size_t)n*32*64 + l;
    const bf16x8* Bl = reinterpret_cast<const bf16x8*>(Wpl) + (size_t)n*32*64 + l;

    f32x4 acc = {0.f, 0.f, 0.f, 0.f};
    #pragma unroll
    for (int ks = 0; ks < 8; ++ks) {
        int kstep = kk*8 + ks;
        bf16x8 ah = Ah[kstep*4];
        bf16x8 al = Al[kstep*4];
        bf16x8 bh = Bh[(size_t)kstep*64];
        bf16x8 bl = Bl[(size_t)kstep*64];
        acc = __builtin_amdgcn_mfma_f32_16x16x32_bf16(ah, bh, acc, 0, 0, 0);
        acc = __builtin_amdgcn_mfma_f32_16x16x32_bf16(ah, bl, acc, 0, 0, 0);
        acc = __builtin_amdgcn_mfma_f32_16x16x32_bf16(al, bh, acc, 0, 0, 0);
    }
    if (kk) red[kk-1][m][l] = acc;
    __syncthreads();
    if (kk == 0) {
        acc += red[0][m][l];
        acc += red[1][m][l];
        acc += red[2][m][l];

        // C/D layout (verified): col = l&15, row = (l>>4)*4 + r
        const int j    = 8*n + ((l & 15) >> 1);     // hidden index
        const bool isf = !(l & 1);                  // even jcat -> Wf column
        const float bfj = bfv[j], bhj = bhv[j];
        #pragma unroll
        for (int r = 0; r < 4; ++r) {
            int b = 16*m + ((l >> 4) << 2) + r;
            float self  = acc[r];
            float other = __shfl_xor(self, 1);
            float sf = (isf ? self : other) + bfj;
            float sh = (isf ? other : self) + bhj;
            float iv = INPt[(size_t)b*HH + j];
            float hn = 1.f/(1.f + expf(-sf)) + tanhf(sh)*iv;
            unsigned short hi = bf16_hi(hn);
            if (isf) {
                hhi_out[(size_t)b*HH + j] = hi;
                if (t == lengths[b] - 1) hselT[(size_t)j*BB + b] = hn;
            } else {
                hlo_out[(size_t)b*HH + j] = bf16_hi(hn - bf16_f(hi));
            }
        }
    }
}

// ---- output projection: lin[b][j] = hsel[b] . Wo[j] + bo[j], hselT is [k][b]
__global__ __launch_bounds__(1024) void outproj_kernel(
    const float* __restrict__ hselT, const float* __restrict__ Wo,
    const float* __restrict__ bov, float* __restrict__ lin)
{
    __shared__ float pf[16][4][64];
    const int tid  = threadIdx.x;
    const int lane = tid & 63;
    const int kq   = __builtin_amdgcn_readfirstlane(tid >> 6);   // 0..15
    const int jg   = blockIdx.x;                                 // 0..255

    const float* w0 = Wo + (size_t)(jg*4+0)*HH + kq*64;
    const float* w1 = Wo + (size_t)(jg*4+1)*HH + kq*64;
    const float* w2 = Wo + (size_t)(jg*4+2)*HH + kq*64;
    const float* w3 = Wo + (size_t)(jg*4+3)*HH + kq*64;
    const float* hb = hselT + (size_t)kq*64*64 + lane;

    float a0=0.f, a1=0.f, a2=0.f, a3=0.f;
    #pragma unroll 8
    for (int kkk = 0; kkk < 64; ++kkk) {
        float hv = hb[(size_t)kkk*64];
        a0 = fmaf(hv, w0[kkk], a0);
        a1 = fmaf(hv, w1[kkk], a1);
        a2 = fmaf(hv, w2[kkk], a2);
        a3 = fmaf(hv, w3[kkk], a3);
    }
    pf[kq][0][lane]=a0; pf[kq][1][lane]=a1; pf[kq][2][lane]=a2; pf[kq][3][lane]=a3;
    __syncthreads();

    const int fc = tid >> 6, fb = tid & 63;
    if (tid < 256) {
        float s = bov[jg*4 + fc];
        #pragma unroll
        for (int q = 0; q < 16; ++q) s += pf[q][fc][fb];
        lin[((size_t)jg*64 + fb)*4 + fc] = s;   // float4 layout [j4][b]
    }
}

__global__ __launch_bounds__(64) void final_kernel(
    const float4* __restrict__ lin, const float* __restrict__ Wlin,
    const float* __restrict__ blin, float* __restrict__ out)
{
    int b = threadIdx.x;
    float l0 = blin[0], l1 = blin[1];
    const float4* w0 = reinterpret_cast<const float4*>(Wlin);
    const float4* w1 = reinterpret_cast<const float4*>(Wlin) + 256;
    #pragma unroll 4
    for (int j4 = 0; j4 < 256; ++j4) {
        float4 v = lin[j4*64 + b];
        float4 wa = w0[j4], wb = w1[j4];
        DOT4(l0, v, wa);
        DOT4(l1, v, wb);
    }
    float m   = fmaxf(l0, l1);
    float lse = m + logf(expf(l0 - m) + expf(l1 - m));
    out[b*2 + 0] = l0 - lse;
    out[b*2 + 1] = l1 - lse;
}

extern "C" void kernel_launch(void* const* d_in, const int* in_sizes, int n_in,
                              void* d_out, int out_size, void* d_ws, size_t ws_size,
                              hipStream_t stream) {
    (void)in_sizes; (void)n_in; (void)out_size; (void)ws_size;
    const int*   x       = (const int*)  d_in[0];
    const int*   lengths = (const int*)  d_in[1];
    const float* emb     = (const float*)d_in[2];
    const float* Wi      = (const float*)d_in[3];
    const float* bi      = (const float*)d_in[4];
    const float* Wf      = (const float*)d_in[5];
    const float* bf      = (const float*)d_in[6];
    const float* Wh      = (const float*)d_in[7];
    const float* bh      = (const float*)d_in[8];
    const float* Wo      = (const float*)d_in[9];
    const float* bo      = (const float*)d_in[10];
    const float* Wlin    = (const float*)d_in[11];
    const float* blin    = (const float*)d_in[12];
    float* out = (float*)d_out;

    char* ws = (char*)d_ws;
    const size_t INP_BYTES = (size_t)SS * BB * HH * sizeof(float);     // 128 MiB
    float*          INP  = (float*)ws;
    unsigned short* Wph  = (unsigned short*)(ws + INP_BYTES);          // 4 MiB
    unsigned short* Wpl  = Wph + (size_t)2*1024*1024;                  // 4 MiB
    unsigned short* hbuf = Wpl + (size_t)2*1024*1024;                  // 4 x 128 KiB
    unsigned short* hhi0 = hbuf;
    unsigned short* hlo0 = hbuf + 65536;
    unsigned short* hhi1 = hbuf + 131072;
    unsigned short* hlo1 = hbuf + 196608;
    float*          hselT= (float*)(hbuf + 262144);                    // 256 KiB
    float*          lin  = hselT + 65536;                              // 256 KiB

    hipMemsetAsync(hbuf, 0, 2*65536*sizeof(unsigned short), stream);   // h(t=0) = 0

    packw_kernel<<<dim3(128, 32), 64, 0, stream>>>(Wf, Wh, Wph, Wpl);
    gemm1_kernel<<<dim3(32, 512), 512, 0, stream>>>(x, emb, Wi, bi, INP);

    for (int t = 0; t < SS; ++t) {
        const unsigned short* ih = (t & 1) ? hhi1 : hhi0;
        const unsigned short* il = (t & 1) ? hlo1 : hlo0;
        unsigned short* oh = (t & 1) ? hhi0 : hhi1;
        unsigned short* ol = (t & 1) ? hlo0 : hlo1;
        step_kernel<<<128, 1024, 0, stream>>>(ih, il, oh, ol, Wph, Wpl,
                                              INP + (size_t)t*BB*HH,
                                              bf, bh, lengths, hselT, t);
    }

    outproj_kernel<<<256, 1024, 0, stream>>>(hselT, Wo, bo, lin);
    final_kernel<<<1, 64, 0, stream>>>((const float4*)lin, Wlin, blin, out);
}